// Round 11
// baseline (326.158 us; speedup 1.0000x reference)
//
#include <hip/hip_runtime.h>
#include <math.h>

typedef unsigned short u16;
typedef unsigned int   u32;
using f32x4  = __attribute__((ext_vector_type(4))) float;
using bf16x8 = __attribute__((ext_vector_type(8))) __bf16;

#define HIDDEN   2880
#define QKVD     5120
#define QD       4096
#define TTOK     2048
#define NKV      8
#define QMULT    8
#define HD       64
#define NPAD     3072   // w_out rows padded to 16*192 -> GEMM2 grid 16x8x2 = 256 blocks

#define PREP_QKV_BLOCKS  14400   // QKVD*HIDDEN/4/256
#define PREP_RMS_BLOCKS  2048

static __device__ __forceinline__ float bflo(u32 u){ return __uint_as_float(u << 16); }
static __device__ __forceinline__ float bfhi(u32 u){ return __uint_as_float(u & 0xffff0000u); }
static __device__ __forceinline__ u16 f2bf(float f){
    u32 u = __float_as_uint(f);
    u32 r = (u + 0x7fffu + ((u >> 16) & 1u)) >> 16;
    return (u16)r;
}

static __device__ __forceinline__ void glds16(const void* g, void* l) {
    __builtin_amdgcn_global_load_lds(
        (__attribute__((address_space(1))) void*)g,
        (__attribute__((address_space(3))) void*)l,
        16, 0, 0);
}

// Mechanics: raw s_barrier (no waitcnt drain), counted vmcnt, sched_barrier pins.
#define SB0()   __builtin_amdgcn_sched_barrier(0)
#define BARB()  do { SB0(); __builtin_amdgcn_s_barrier(); SB0(); } while (0)
#define LGKM0() do { asm volatile("s_waitcnt lgkmcnt(0)"); SB0(); } while (0)
#define VMW(N)  do { SB0(); asm volatile("s_waitcnt vmcnt(" #N ")"); SB0(); } while (0)

// ---------------- fused prep: w_qkv cvt | rmsnorm ----------------
__global__ __launch_bounds__(256) void prep_kernel(const float* __restrict__ w_qkv,
                                                   u16* __restrict__ wqkv_bf,
                                                   const float* __restrict__ x,
                                                   const float* __restrict__ scale,
                                                   u16* __restrict__ h) {
    const int b = blockIdx.x;
    const int tid = threadIdx.x;
    if (b < PREP_QKV_BLOCKS) {
        int i = b * 256 + tid;
        float4 f = ((const float4*)w_qkv)[i];
        ushort4 o;
        o.x = f2bf(f.x); o.y = f2bf(f.y); o.z = f2bf(f.z); o.w = f2bf(f.w);
        ((ushort4*)wqkv_bf)[i] = o;
    } else {
        const int t = b - PREP_QKV_BLOCKS;
        const float4* xr = (const float4*)(x + (long)t * HIDDEN);
        float4 v[3];
        float ss = 0.f;
        #pragma unroll
        for (int it = 0; it < 3; ++it) {
            int i4 = tid + it * 256;
            if (i4 < 720) {
                v[it] = xr[i4];
                ss += v[it].x*v[it].x + v[it].y*v[it].y + v[it].z*v[it].z + v[it].w*v[it].w;
            }
        }
        #pragma unroll
        for (int off = 32; off > 0; off >>= 1) ss += __shfl_down(ss, off);
        __shared__ float red[4];
        if ((tid & 63) == 0) red[tid >> 6] = ss;
        __syncthreads();
        float tot = red[0] + red[1] + red[2] + red[3];
        float rr = rsqrtf(tot * (1.0f / HIDDEN) + 1e-5f);
        ushort4* hr = (ushort4*)(h + (long)t * HIDDEN);
        #pragma unroll
        for (int it = 0; it < 3; ++it) {
            int i4 = tid + it * 256;
            if (i4 < 720) {
                float4 s4 = ((const float4*)scale)[i4];
                ushort4 o;
                o.x = f2bf(v[it].x * rr * s4.x);
                o.y = f2bf(v[it].y * rr * s4.y);
                o.z = f2bf(v[it].z * rr * s4.z);
                o.w = f2bf(v[it].w * rr * s4.w);
                hr[i4] = o;
            }
        }
    }
}

// -- R6 GEMM (GEMM1; 83-85us): phase-ahead register-pipelined 256x256/BK=64,
// 2 barriers/K-tile. nfill=96 filler blocks (idle CUs) do the w_out cvt.
// UNCHANGED (anchor).

#define READ_BQ(SET, BASE, NQ) do { \
    SET[0][0] = *(const bf16x8*)((BASE) + (2*(NQ)+0)*2048 + off0); \
    SET[0][1] = *(const bf16x8*)((BASE) + (2*(NQ)+0)*2048 + off1); \
    SET[1][0] = *(const bf16x8*)((BASE) + (2*(NQ)+1)*2048 + off0); \
    SET[1][1] = *(const bf16x8*)((BASE) + (2*(NQ)+1)*2048 + off1); \
} while (0)

#define READ_AQ(BASE) do { \
    _Pragma("unroll") \
    for (int mi_ = 0; mi_ < 4; ++mi_) { \
        aq[mi_][0] = *(const bf16x8*)((BASE) + mi_*2048 + off0); \
        aq[mi_][1] = *(const bf16x8*)((BASE) + mi_*2048 + off1); \
    } \
} while (0)

#define MFMA_N(NQ, SET) do { \
    __builtin_amdgcn_s_setprio(1); \
    _Pragma("unroll") \
    for (int mi_ = 0; mi_ < 4; ++mi_) { \
        _Pragma("unroll") \
        for (int j_ = 0; j_ < 2; ++j_) { \
            acc[mi_][2*(NQ)+j_] = __builtin_amdgcn_mfma_f32_16x16x32_bf16(aq[mi_][0], SET[j_][0], acc[mi_][2*(NQ)+j_], 0, 0, 0); \
            acc[mi_][2*(NQ)+j_] = __builtin_amdgcn_mfma_f32_16x16x32_bf16(aq[mi_][1], SET[j_][1], acc[mi_][2*(NQ)+j_], 0, 0, 0); \
        } \
    } \
    __builtin_amdgcn_s_setprio(0); \
} while (0)

__global__ __launch_bounds__(512, 2) void gemm_bt_8ph(const u16* __restrict__ A,
                                                      const u16* __restrict__ B,
                                                      u16* __restrict__ C0,
                                                      int N, int K, int ksplit,
                                                      int blimit, int colmax,
                                                      int nz_gemm, int nfill,
                                                      const float* __restrict__ wout_src,
                                                      u16* __restrict__ wout_dst) {
    const int tid  = threadIdx.x;

    if ((int)blockIdx.z >= nz_gemm) {
        long bidx = (long)blockIdx.y * gridDim.x + blockIdx.x;
        if (bidx >= nfill) return;
        long i = bidx * 512 + tid;
        const long tot = (long)NPAD * QD / 4;
        const long stride = (long)nfill * 512;
        for (; i < tot; i += stride) {
            long idx = i * 4;
            int row = (int)(idx >> 12);
            int col = (int)(idx & 4095);
            ushort4 o;
            if (row < HIDDEN) {
                float4 f = *(const float4*)(wout_src + (long)row * QD + col);
                o.x = f2bf(f.x); o.y = f2bf(f.y); o.z = f2bf(f.z); o.w = f2bf(f.w);
            } else {
                o.x = 0; o.y = 0; o.z = 0; o.w = 0;
            }
            ((ushort4*)wout_dst)[i] = o;
        }
        return;
    }

    extern __shared__ u16 smem[];
    u16* const smA = smem;                  // [2][256][64] bf16 (32 KB/slot)
    u16* const smB = smem + 2 * 256 * 64;   // byte 65536, [2][256][64]
    const int lane = tid & 63;
    const int wv   = tid >> 6;              // wave 0..7
    const int wm2  = wv >> 1;               // 0..3 (M quad, 64 rows)
    const int wn2  = wv & 1;                // 0..1 (N half, 128 cols)
    const long m0  = (long)blockIdx.y * 256;
    const long n0  = (long)blockIdx.x * 256;
    const int kbase = blockIdx.z * ksplit;
    int krem = K - kbase; if (krem > ksplit) krem = ksplit;
    const int NT   = krem >> 6;             // K-tiles of 64
    u16* C = C0 + (size_t)blockIdx.z * ((size_t)TTOK * N);

    const int srow = tid >> 3;                              // 0..63
    const int sg8  = ((tid & 7) ^ (srow & 7)) << 3;         // src elem offset
    const int fr   = lane & 15;
    const int off0 = ((lane >> 4) << 4) ^ ((lane & 7) << 4);
    const int off1 = off0 ^ 64;
    const char* aR = (const char*)smA + (wm2 * 64  + fr) * 128;
    const char* bR = (const char*)smB + (wn2 * 128 + fr) * 128;

    f32x4 acc[4][8];
    #pragma unroll
    for (int i = 0; i < 4; ++i)
        #pragma unroll
        for (int j = 0; j < 8; ++j) acc[i][j] = f32x4{0.f, 0.f, 0.f, 0.f};

    const u16* Asrc = A + (m0 + srow) * (long)K + kbase + sg8;
    auto stageA = [&](int t) {
        char* dst = (char*)smA + (t & 1) * 32768 + wv * 1024;
        const u16* src = Asrc + t * 64;
        #pragma unroll
        for (int hj = 0; hj < 4; ++hj)
            glds16(src + (size_t)(hj * 64) * K, dst + hj * 8192);
    };
    auto stageBh = [&](int t, int h) {
        char* dst = (char*)smB + (t & 1) * 32768 + (h * 128 + wv * 8) * 128;
        #pragma unroll
        for (int j = 0; j < 2; ++j) {
            long r = n0 + h * 128 + j * 64 + srow;
            if (r > blimit) r = blimit;
            glds16(B + (size_t)r * K + kbase + t * 64 + sg8, dst + j * 8192);
        }
    };

    bf16x8 aq[4][2], bqE[2][2], bqO[2][2];

    stageA(0);
    stageBh(0, 0); stageBh(0, 1);
    if (NT > 1) {
        stageA(1);
        stageBh(1, 0);
        VMW(6);
    } else {
        VMW(0);
    }
    BARB();
    READ_BQ(bqE, bR, 0);
    READ_AQ(aR);
    LGKM0();
    BARB();

    for (int t = 0; t < NT; ++t) {
        const char* aS1 = aR + ((t + 1) & 1) * 32768;
        const char* bS  = bR + (t & 1) * 32768;
        const char* bS1 = bR + ((t + 1) & 1) * 32768;
        READ_BQ(bqO, bS, 1);
        if (t + 1 < NT) stageBh(t + 1, 1);
        if (t + 2 < NT) stageA(t + 2);
        MFMA_N(0, bqE);
        SB0();
        READ_BQ(bqE, bS, 2);
        MFMA_N(1, bqO);
        SB0();
        READ_BQ(bqO, bS, 3);
        MFMA_N(2, bqE);
        if (t + 2 < NT)      VMW(4);
        else if (t + 1 < NT) VMW(0);
        BARB();
        if (t + 1 < NT) READ_BQ(bqE, bS1, 0);
        if (t + 2 < NT) stageBh(t + 2, 0);
        MFMA_N(3, bqO);
        if (t + 1 < NT) READ_AQ(aS1);
        LGKM0();
        BARB();
    }

    const int cr = (lane >> 4) * 4;
    const int cc = lane & 15;
    #pragma unroll
    for (int nf = 0; nf < 8; ++nf) {
        long col = n0 + wn2 * 128 + nf * 16 + cc;
        if (col < colmax) {
            #pragma unroll
            for (int mi = 0; mi < 4; ++mi) {
                long row = m0 + wm2 * 64 + mi * 16 + cr;
                #pragma unroll
                for (int r2 = 0; r2 < 4; ++r2)
                    C[(row + r2) * (long)N + col] = f2bf(acc[mi][nf][r2]);
            }
        }
    }
}

// -- GEMM2 (R10, verified): 256x192 tile (3 B-quads), full-fill 16x8x2=256 ----
__global__ __launch_bounds__(512, 2) void gemm_bt_3q(const u16* __restrict__ A,
                                                     const u16* __restrict__ B,
                                                     u16* __restrict__ C0,
                                                     int N, int K, int ksplit,
                                                     int blimit) {
    extern __shared__ u16 smem[];
    u16* const smA = smem;                  // [2][256][64] (32 KB/slot)
    u16* const smB = smem + 2 * 256 * 64;   // [2][192][64] (24 KB/slot)
    const int tid  = threadIdx.x;
    const int lane = tid & 63;
    const int wv   = tid >> 6;
    const int wm2  = wv >> 1;
    const int wn2  = wv & 1;
    const long m0  = (long)blockIdx.y * 256;
    const long n0  = (long)blockIdx.x * 192;
    const int kbase = blockIdx.z * ksplit;
    int krem = K - kbase; if (krem > ksplit) krem = ksplit;
    const int NT   = krem >> 6;
    u16* C = C0 + (size_t)blockIdx.z * ((size_t)TTOK * N);

    const int srow = tid >> 3;
    const int sg8  = ((tid & 7) ^ (srow & 7)) << 3;
    const int fr   = lane & 15;
    const int off0 = ((lane >> 4) << 4) ^ ((lane & 7) << 4);
    const int off1 = off0 ^ 64;
    const char* aR = (const char*)smA + (wm2 * 64 + fr) * 128;
    const char* bR = (const char*)smB + (wn2 * 96 + fr) * 128;

    f32x4 acc[4][6];
    #pragma unroll
    for (int i = 0; i < 4; ++i)
        #pragma unroll
        for (int j = 0; j < 6; ++j) acc[i][j] = f32x4{0.f, 0.f, 0.f, 0.f};

    const u16* Asrc = A + (m0 + srow) * (long)K + kbase + sg8;
    auto stageA = [&](int t) {
        char* dst = (char*)smA + (t & 1) * 32768 + wv * 1024;
        const u16* src = Asrc + t * 64;
        #pragma unroll
        for (int hj = 0; hj < 4; ++hj)
            glds16(src + (size_t)(hj * 64) * K, dst + hj * 8192);
    };
    auto stageB3 = [&](int t) {
        char* base = (char*)smB + (t & 1) * 24576;
        #pragma unroll
        for (int j = 0; j < 3; ++j) {
            long r = n0 + j * 64 + srow;
            if (r > blimit) r = blimit;
            glds16(B + (size_t)r * K + kbase + t * 64 + sg8,
                   base + (j * 64 + wv * 8) * 128);
        }
    };

    bf16x8 aq[4][2], s0[2][2], s1[2][2], s2[2][2];

    stageB3(0);
    stageA(0);
    if (NT > 1) { stageA(1); VMW(4); }
    else        { VMW(0); }
    BARB();
    READ_BQ(s2, bR, 0);
    READ_AQ(aR);
    LGKM0();
    BARB();

    for (int t = 0; t < NT; ++t) {
        const char* aS1 = aR + ((t + 1) & 1) * 32768;
        const char* bS  = bR + (t & 1) * 24576;
        const char* bS1 = bR + ((t + 1) & 1) * 24576;
        READ_BQ(s0, bS, 1);
        if (t + 1 < NT) stageB3(t + 1);
        if (t + 2 < NT) stageA(t + 2);
        MFMA_N(0, s2);
        SB0();
        READ_BQ(s1, bS, 2);
        MFMA_N(1, s0);
        SB0();
        MFMA_N(2, s1);
        if (t + 2 < NT)      VMW(4);
        else if (t + 1 < NT) VMW(0);
        BARB();
        if (t + 1 < NT) { READ_BQ(s2, bS1, 0); READ_AQ(aS1); }
        LGKM0();
        BARB();
    }

    const int cr = (lane >> 4) * 4;
    const int cc = lane & 15;
    #pragma unroll
    for (int nf = 0; nf < 6; ++nf) {
        long col = n0 + wn2 * 96 + nf * 16 + cc;
        #pragma unroll
        for (int mi = 0; mi < 4; ++mi) {
            long row = m0 + wm2 * 64 + mi * 16 + cr;
            #pragma unroll
            for (int r2 = 0; r2 < 4; ++r2)
                C[(row + r2) * (long)N + col] = f2bf(acc[mi][nf][r2]);
        }
    }
}

// -------- R11 attn: rope FUSED (reads GEMM1 p1 + b_qkv directly) ---------------
// Eliminates the rope dispatch and the qrot/krot/vrot round-trip (~42 MB).
// Per block: cos/sin table [144][32] f32 (36 KB LDS; tokens t0-128..t0+15,
// clamped negatives use token 0 -- rows masked anyway). Phase A: V staging
// (bias only) + table fill (sincos hides under V's global loads). Phase B:
// K staging (bias+rotate into ks) + Q load (bias+rotate in regs, static idx).
// Rounding points identical to the split rope kernel -> bit-identical numerics.
// LDS total 122112 B -> still 1 block/CU.
__global__ __launch_bounds__(512, 1) void attn_kernel(const u16* __restrict__ p1,
                                                      const float* __restrict__ b_qkv,
                                                      const float* __restrict__ sinks,
                                                      u16* __restrict__ o) {
    const int t0  = blockIdx.x * 16;
    const int h   = blockIdx.y;
    const int tid = threadIdx.x;
    const int lane = tid & 63, wv = tid >> 6;    // wv = q-head 0..7
    extern __shared__ __align__(16) u16 asmem[];
    u16* const ks = asmem;                        // [144][72]
    u16* const Vt = asmem + 10368;                // [64][168], cols 144..159 zero
    u16* const Pb = asmem + 21120;                // [8][16][168], cols 144..159 zero
    float* const csT = (float*)(asmem + 42624);   // [144][32]
    float* const snT = csT + 4608;                // [144][32]

    // ---- phase A: V staging (bias, pair-pack) + rope table fill + pads ----
    if (tid < 288) {
        const int kp = tid >> 2, c2 = tid & 3;   // kp 0..71, c2 0..3
        const int k0 = kp * 2;
        int tk0 = t0 - 128 + k0;     tk0 = tk0 < 0 ? 0 : tk0;
        int tk1 = t0 - 128 + k0 + 1; tk1 = tk1 < 0 ? 0 : tk1;
        const u16* v0 = p1 + (long)tk0 * QKVD + QD + 512 + h * 64 + c2 * 16;
        const u16* v1 = p1 + (long)tk1 * QKVD + QD + 512 + h * 64 + c2 * 16;
        uint4 a0 = *(const uint4*)(v0);
        uint4 a1 = *(const uint4*)(v0 + 8);
        uint4 b0 = *(const uint4*)(v1);
        uint4 b1 = *(const uint4*)(v1 + 8);
        u32 wa[8] = {a0.x, a0.y, a0.z, a0.w, a1.x, a1.y, a1.z, a1.w};
        u32 wb[8] = {b0.x, b0.y, b0.z, b0.w, b1.x, b1.y, b1.z, b1.w};
        const float* bv = b_qkv + QD + 512 + h * 64 + c2 * 16;
        u16* vrow = Vt + c2 * 16 * 168 + k0;
        #pragma unroll
        for (int d = 0; d < 16; ++d) {
            float fa = ((d & 1) ? bfhi(wa[d >> 1]) : bflo(wa[d >> 1])) + bv[d];
            float fb = ((d & 1) ? bfhi(wb[d >> 1]) : bflo(wb[d >> 1])) + bv[d];
            *(u32*)(vrow + d * 168) = (u32)f2bf(fa) | ((u32)f2bf(fb) << 16);
        }
    }
    #pragma unroll
    for (int ii = 0; ii < 9; ++ii) {             // 4608 table entries / 512 thr
        int idx = ii * 512 + tid;
        int tok = idx >> 5, fi = idx & 31;
        float f = (float)fi;
        float freq   = exp2f(17.1946032f * (f * (1.0f / 32.0f)));
        float interp = 1.0f / (32.0f * freq);
        float extra  = 1.0f / freq;
        float ramp   = (f - 8.0927802f) * (1.0f / (17.3980220f - 8.0927802f));
        float rc     = fminf(fmaxf(ramp, 0.0f), 1.0f);
        float invf   = interp * rc + extra * (1.0f - rc);
        int t = t0 - 128 + tok; if (t < 0) t = 0;
        float ang = (float)t * invf;
        csT[idx] = cosf(ang) * 1.3465736f;
        snT[idx] = sinf(ang) * 1.3465736f;
    }
    if (tid < 128) {
        *(uint4*)(Vt + (tid >> 1) * 168 + 144 + (tid & 1) * 8) = uint4{0, 0, 0, 0};
    }
    if (lane < 32) {
        *(uint4*)(Pb + wv * 16 * 168 + (lane >> 1) * 168 + 144 + (lane & 1) * 8) = uint4{0, 0, 0, 0};
    }
    __syncthreads();

    // ---- phase B: K staging (bias+rotate) + Q fragments (bias+rotate) ----
    #pragma unroll
    for (int ii = 0; ii < 9; ++ii) {             // 144 rows x 32 pairs / 512 thr
        int idx = ii * 512 + tid;
        int rr = idx >> 5, i = idx & 31;
        int tk = t0 - 128 + rr;
        int tks = tk < 0 ? 0 : tk;               // clamped; masked later
        u32 w = *(const u32*)(p1 + (long)tks * QKVD + QD + h * 64 + 2 * i);
        float b0 = b_qkv[QD + h * 64 + 2 * i];
        float b1 = b_qkv[QD + h * 64 + 2 * i + 1];
        float c = csT[rr * 32 + i], s = snT[rr * 32 + i];
        float a0 = bflo(w) + b0, a1 = bfhi(w) + b1;
        *(u32*)(ks + rr * 72 + 2 * i) =
            (u32)f2bf(a0 * c - a1 * s) | ((u32)f2bf(a1 * c + a0 * s) << 16);
    }

    const int head = h * QMULT + wv;
    const int fr = lane & 15, fk = (lane >> 4) * 8;
    const int cr = (lane >> 4) * 4;
    u16* const Pw = Pb + wv * 16 * 168;

    // Q: load from p1, add bias, rotate (all indices compile-time, rule #20)
    const u16* qrow = p1 + (long)(t0 + fr) * QKVD + head * HD;
    const float* bq = b_qkv + head * HD;
    const float* csQ = csT + (128 + fr) * 32;
    const float* snQ = snT + (128 + fr) * 32;
    u16 qtmp[16];
    #pragma unroll
    for (int half = 0; half < 2; ++half) {
        #pragma unroll
        for (int j = 0; j < 4; ++j) {
            const int base = half * 32 + fk;       // fk is per-lane, base+2j dims
            u32 w = *(const u32*)(qrow + base + 2 * j);
            float a0 = bflo(w) + bq[base + 2 * j];
            float a1 = bfhi(w) + bq[base + 2 * j + 1];
            float c = csQ[(base >> 1) + j], s = snQ[(base >> 1) + j];
            qtmp[half * 8 + 2 * j]     = f2bf(a0 * c - a1 * s);
            qtmp[half * 8 + 2 * j + 1] = f2bf(a1 * c + a0 * s);
        }
    }
    bf16x8 qf0 = *(const bf16x8*)&qtmp[0];
    bf16x8 qf1 = *(const bf16x8*)&qtmp[8];
    __syncthreads();

    const int kmin = 128 - t0;
    float lsum[4] = {0.f, 0.f, 0.f, 0.f};

    for (int nt = 0; nt < 9; ++nt) {
        bf16x8 b0 = *(const bf16x8*)(ks + (nt * 16 + fr) * 72 + fk);
        bf16x8 b1 = *(const bf16x8*)(ks + (nt * 16 + fr) * 72 + 32 + fk);
        f32x4 s = f32x4{0.f, 0.f, 0.f, 0.f};
        s = __builtin_amdgcn_mfma_f32_16x16x32_bf16(qf0, b0, s, 0, 0, 0);
        s = __builtin_amdgcn_mfma_f32_16x16x32_bf16(qf1, b1, s, 0, 0, 0);
        const int kk = nt * 16 + fr;
        #pragma unroll
        for (int r = 0; r < 4; ++r) {
            int row = cr + r;
            bool valid = (kk >= row) && (kk <= row + 128) && (kk >= kmin);
            float p = valid ? __expf(s[r] * 0.125f) : 0.0f;
            lsum[r] += p;
            Pw[row * 168 + kk] = f2bf(p);
        }
    }

    f32x4 oacc[4];
    #pragma unroll
    for (int dt = 0; dt < 4; ++dt) oacc[dt] = f32x4{0.f, 0.f, 0.f, 0.f};
    #pragma unroll
    for (int k5 = 0; k5 < 5; ++k5) {
        const int k0 = k5 * 32;
        bf16x8 pa = *(const bf16x8*)(Pw + fr * 168 + k0 + fk);
        #pragma unroll
        for (int dt = 0; dt < 4; ++dt) {
            bf16x8 vf = *(const bf16x8*)(Vt + (dt * 16 + fr) * 168 + k0 + fk);
            oacc[dt] = __builtin_amdgcn_mfma_f32_16x16x32_bf16(pa, vf, oacc[dt], 0, 0, 0);
        }
    }

    #pragma unroll
    for (int r = 0; r < 4; ++r) {
        float v = lsum[r];
        v += __shfl_xor(v, 1);
        v += __shfl_xor(v, 2);
        v += __shfl_xor(v, 4);
        v += __shfl_xor(v, 8);
        lsum[r] = v;
    }
    const float sk = exp2f(sinks[head]);
    float inv[4];
    #pragma unroll
    for (int r = 0; r < 4; ++r) inv[r] = 1.0f / (lsum[r] + sk);

    #pragma unroll
    for (int dt = 0; dt < 4; ++dt) {
        #pragma unroll
        for (int r = 0; r < 4; ++r) {
            o[(long)(t0 + cr + r) * QD + head * HD + dt * 16 + fr] = f2bf(oacc[dt][r] * inv[r]);
        }
    }
}

// ---------------- reduce GEMM2 partials + bias + residual -> out ----------------
__global__ __launch_bounds__(256) void reduce2_kernel(const u16* __restrict__ p2a,
                                                      const u16* __restrict__ p2b,
                                                      const float* __restrict__ x,
                                                      const float* __restrict__ b_out,
                                                      float* __restrict__ out) {
    const int row = blockIdx.y;
    const int c4 = blockIdx.x * 256 + threadIdx.x;   // float4 index within row
    if (c4 >= 720) return;
    const int col = c4 * 4;
    ushort4 ua = *(const ushort4*)(p2a + (long)row * NPAD + col);
    ushort4 ub = *(const ushort4*)(p2b + (long)row * NPAD + col);
    float4 xv = *(const float4*)(x + (long)row * HIDDEN + col);
    float4 bv = *(const float4*)(b_out + col);
    float4 o;
    o.x = xv.x + bv.x + __uint_as_float((u32)ua.x << 16) + __uint_as_float((u32)ub.x << 16);
    o.y = xv.y + bv.y + __uint_as_float((u32)ua.y << 16) + __uint_as_float((u32)ub.y << 16);
    o.z = xv.z + bv.z + __uint_as_float((u32)ua.z << 16) + __uint_as_float((u32)ub.z << 16);
    o.w = xv.w + bv.w + __uint_as_float((u32)ua.w << 16) + __uint_as_float((u32)ub.w << 16);
    *(float4*)(out + (long)row * HIDDEN + col) = o;
}

// ---------------- launcher ----------------
extern "C" void kernel_launch(void* const* d_in, const int* in_sizes, int n_in,
                              void* d_out, int out_size, void* d_ws, size_t ws_size,
                              hipStream_t stream) {
    const float* x      = (const float*)d_in[0];
    const float* nscale = (const float*)d_in[1];
    const float* w_qkv  = (const float*)d_in[2];
    const float* b_qkv  = (const float*)d_in[3];
    const float* sinks  = (const float*)d_in[4];
    const float* w_out  = (const float*)d_in[5];
    const float* b_out  = (const float*)d_in[6];
    float* out = (float*)d_out;

    static int smem_set = 0;
    if (!smem_set) {
        hipFuncSetAttribute((const void*)gemm_bt_8ph,
                            hipFuncAttributeMaxDynamicSharedMemorySize, 131072);
        hipFuncSetAttribute((const void*)gemm_bt_3q,
                            hipFuncAttributeMaxDynamicSharedMemorySize, 114688);
        hipFuncSetAttribute((const void*)attn_kernel,
                            hipFuncAttributeMaxDynamicSharedMemorySize, 122112);
        smem_set = 1;
    }

    char* ws = (char*)d_ws;
    size_t off = 0;
    auto alloc = [&](size_t bytes) { void* p = ws + off; off += (bytes + 255) & ~(size_t)255; return p; };
    const size_t p1_bytes  = (size_t)TTOK * QKVD * 2;          // 21.0 MB (GEMM1 out)
    const size_t p2_bytes  = (size_t)2 * TTOK * NPAD * 2;      // 25.2 MB (GEMM2 partials)
    u16* wqkv_bf = (u16*)alloc((size_t)QKVD * HIDDEN * 2);     // 29.5 MB
    u16* wout_bf = (u16*)alloc((size_t)NPAD * QD * 2);         // 25.2 MB
    u16* h       = (u16*)alloc((size_t)TTOK * HIDDEN * 2);     // 11.8 MB
    u16* p1      = (u16*)alloc(p1_bytes > p2_bytes ? p1_bytes : p2_bytes);
    // aliases (dead-after analysis):
    u16* attn = wqkv_bf;               // wqkv_bf dead after gemm1; attn [2048][4096] = 16.8 MB
    u16* p2   = p1;                    // p1 dead after attn (attn reads p1; GEMM2 writes after)

    prep_kernel<<<PREP_QKV_BLOCKS + PREP_RMS_BLOCKS, 256, 0, stream>>>(
        w_qkv, wqkv_bf, x, nscale, h);
    // GEMM1: full-K, 160 gemm blocks + 96 working filler blocks (z=1; rest exit)
    gemm_bt_8ph<<<dim3(QKVD / 256, TTOK / 256, 2), 512, 131072, stream>>>(
        h, wqkv_bf, p1, QKVD, HIDDEN, HIDDEN, QKVD - 1, QKVD, 1, 96, w_out, wout_bf);
    // attn (rope fused): 128x8 = 1024 blocks x 512 thr, 122 KB dynamic LDS
    attn_kernel<<<dim3(TTOK / 16, NKV), 512, 122112, stream>>>(
        p1, b_qkv, sinks, attn);
    // GEMM2: 256x192 tiles, split-K z=2 -> 16x8x2 = 256 blocks (full fill)
    gemm_bt_3q<<<dim3(NPAD / 192, TTOK / 256, 2), 512, 114688, stream>>>(
        attn, wout_bf, p2, NPAD, QD, QD / 2, NPAD - 1);
    reduce2_kernel<<<dim3(3, TTOK), 256, 0, stream>>>(
        p2, p2 + (size_t)TTOK * NPAD, x, b_out, out);
}

// Round 12
// 319.165 us; speedup vs baseline: 1.0219x; 1.0219x over previous
//
#include <hip/hip_runtime.h>
#include <math.h>

typedef unsigned short u16;
typedef unsigned int   u32;
using f32x4  = __attribute__((ext_vector_type(4))) float;
using bf16x8 = __attribute__((ext_vector_type(8))) __bf16;

#define HIDDEN   2880
#define QKVD     5120
#define QD       4096
#define TTOK     2048
#define NKV      8
#define QMULT    8
#define HD       64
#define NPAD     3072   // w_out rows padded to 16*192 -> GEMM2 grid 16x8x2 = 256 blocks

#define PREP_QKV_BLOCKS  14400   // QKVD*HIDDEN/4/256
#define PREP_RMS_BLOCKS  2048

static __device__ __forceinline__ float bflo(u32 u){ return __uint_as_float(u << 16); }
static __device__ __forceinline__ float bfhi(u32 u){ return __uint_as_float(u & 0xffff0000u); }
static __device__ __forceinline__ u16 f2bf(float f){
    u32 u = __float_as_uint(f);
    u32 r = (u + 0x7fffu + ((u >> 16) & 1u)) >> 16;
    return (u16)r;
}

static __device__ __forceinline__ void glds16(const void* g, void* l) {
    __builtin_amdgcn_global_load_lds(
        (__attribute__((address_space(1))) void*)g,
        (__attribute__((address_space(3))) void*)l,
        16, 0, 0);
}

// Mechanics: raw s_barrier (no waitcnt drain), counted vmcnt, sched_barrier pins.
#define SB0()   __builtin_amdgcn_sched_barrier(0)
#define BARB()  do { SB0(); __builtin_amdgcn_s_barrier(); SB0(); } while (0)
#define VMW(N)  do { SB0(); asm volatile("s_waitcnt vmcnt(" #N ")"); SB0(); } while (0)

// ---------------- fused prep: w_qkv cvt | rmsnorm ----------------
__global__ __launch_bounds__(256) void prep_kernel(const float* __restrict__ w_qkv,
                                                   u16* __restrict__ wqkv_bf,
                                                   const float* __restrict__ x,
                                                   const float* __restrict__ scale,
                                                   u16* __restrict__ h) {
    const int b = blockIdx.x;
    const int tid = threadIdx.x;
    if (b < PREP_QKV_BLOCKS) {
        int i = b * 256 + tid;
        float4 f = ((const float4*)w_qkv)[i];
        ushort4 o;
        o.x = f2bf(f.x); o.y = f2bf(f.y); o.z = f2bf(f.z); o.w = f2bf(f.w);
        ((ushort4*)wqkv_bf)[i] = o;
    } else {
        const int t = b - PREP_QKV_BLOCKS;
        const float4* xr = (const float4*)(x + (long)t * HIDDEN);
        float4 v[3];
        float ss = 0.f;
        #pragma unroll
        for (int it = 0; it < 3; ++it) {
            int i4 = tid + it * 256;
            if (i4 < 720) {
                v[it] = xr[i4];
                ss += v[it].x*v[it].x + v[it].y*v[it].y + v[it].z*v[it].z + v[it].w*v[it].w;
            }
        }
        #pragma unroll
        for (int off = 32; off > 0; off >>= 1) ss += __shfl_down(ss, off);
        __shared__ float red[4];
        if ((tid & 63) == 0) red[tid >> 6] = ss;
        __syncthreads();
        float tot = red[0] + red[1] + red[2] + red[3];
        float rr = rsqrtf(tot * (1.0f / HIDDEN) + 1e-5f);
        ushort4* hr = (ushort4*)(h + (long)t * HIDDEN);
        #pragma unroll
        for (int it = 0; it < 3; ++it) {
            int i4 = tid + it * 256;
            if (i4 < 720) {
                float4 s4 = ((const float4*)scale)[i4];
                ushort4 o;
                o.x = f2bf(v[it].x * rr * s4.x);
                o.y = f2bf(v[it].y * rr * s4.y);
                o.z = f2bf(v[it].z * rr * s4.z);
                o.w = f2bf(v[it].w * rr * s4.w);
                hr[i4] = o;
            }
        }
    }
}

// -- R12 GEMM1: R6 phase-ahead + 3 A-SLOTS + NO in-loop lgkmcnt(0) --------------
// R6's LGKM0 before the ph4-end barrier serialized ~1150cy of cross-wave LDS
// drain per tile (every wave's 12 ds_reads retired before ANY wave proceeds).
// With 3 A-slots every slot-write lands >=1 full tile + 2 barriers after the
// previous occupant's reads -- and those reads were already retired by the
// consuming MFMA's compiler-inserted counted lgkm wait (in-wave). So LGKM0 is
// removable, and each wave's ph4 reads drain on the LDS pipe UNDER other waves'
// MFMAs (cross-wave skew R6 still blocked).
// Schedule (tile t), reads feed NEXT phase's MFMA:
//  ph1: read q1->O; stage Bh0(t+1),Bh1(t+1),A(t+2->slot (t+2)%3); MFMA q0(E)
//  ph2: read q2->E; MFMA q1(O)
//  ph3: read q3->O; MFMA q2(E); VMW(4); BARB
//  ph4: read B(t+1).q0->E; MFMA q3(O); read aq<-A(t+1); BARB
// VMW(4)@ph3(t): per-wave outstanding = A(t+1)[4, ph1(t-1)] + B(t+1)[4, ph1(t)]
//  + A(t+2)[4, ph1(t)] = 12 -> leaves newest 4 (A(t+2)); A(t+1)+B(t+1)
//  confirmed before ph4 reads them; BARB propagates cross-wave.
//  Tails: t+2>=NT -> VMW(0); t+1>=NT -> skip (nothing pending needed).
// Write-safety (no LGKM0 needed):
//  B slot (t+1)&1, written ph1(t): last reads = tile t-1's q1/q2/q3, each
//   consumed by an MFMA one phase later (last: MFMA_N(3)@ph4(t-1), per-wave
//   lgkm-retired), + BARB@ph4(t-1)-end before the write issues.
//  A slot (t+2)%3, written ph1(t): last reads = tile t-1's aq @ph4(t-2),
//   consumed by MFMA_N(0)@ph1(t-1) (per-wave retired), + 2 barriers since.
// LDS 160 KB exactly: A[3][256][64] (96K) + B[2][256][64] (64K).

#define READ_BQ(SET, BASE, NQ) do { \
    SET[0][0] = *(const bf16x8*)((BASE) + (2*(NQ)+0)*2048 + off0); \
    SET[0][1] = *(const bf16x8*)((BASE) + (2*(NQ)+0)*2048 + off1); \
    SET[1][0] = *(const bf16x8*)((BASE) + (2*(NQ)+1)*2048 + off0); \
    SET[1][1] = *(const bf16x8*)((BASE) + (2*(NQ)+1)*2048 + off1); \
} while (0)

#define READ_AQ(BASE) do { \
    _Pragma("unroll") \
    for (int mi_ = 0; mi_ < 4; ++mi_) { \
        aq[mi_][0] = *(const bf16x8*)((BASE) + mi_*2048 + off0); \
        aq[mi_][1] = *(const bf16x8*)((BASE) + mi_*2048 + off1); \
    } \
} while (0)

#define MFMA_N(NQ, SET) do { \
    __builtin_amdgcn_s_setprio(1); \
    _Pragma("unroll") \
    for (int mi_ = 0; mi_ < 4; ++mi_) { \
        _Pragma("unroll") \
        for (int j_ = 0; j_ < 2; ++j_) { \
            acc[mi_][2*(NQ)+j_] = __builtin_amdgcn_mfma_f32_16x16x32_bf16(aq[mi_][0], SET[j_][0], acc[mi_][2*(NQ)+j_], 0, 0, 0); \
            acc[mi_][2*(NQ)+j_] = __builtin_amdgcn_mfma_f32_16x16x32_bf16(aq[mi_][1], SET[j_][1], acc[mi_][2*(NQ)+j_], 0, 0, 0); \
        } \
    } \
    __builtin_amdgcn_s_setprio(0); \
} while (0)

__global__ __launch_bounds__(512, 2) void gemm_bt_8ph(const u16* __restrict__ A,
                                                      const u16* __restrict__ B,
                                                      u16* __restrict__ C0,
                                                      int N, int K, int ksplit,
                                                      int blimit, int colmax,
                                                      int nz_gemm, int nfill,
                                                      const float* __restrict__ wout_src,
                                                      u16* __restrict__ wout_dst) {
    const int tid  = threadIdx.x;

    if ((int)blockIdx.z >= nz_gemm) {
        // ---- filler blocks: w_out cvt+pad [HIDDEN][QD] f32 -> [NPAD][QD] bf16 ----
        long bidx = (long)blockIdx.y * gridDim.x + blockIdx.x;
        if (bidx >= nfill) return;
        long i = bidx * 512 + tid;
        const long tot = (long)NPAD * QD / 4;
        const long stride = (long)nfill * 512;
        for (; i < tot; i += stride) {
            long idx = i * 4;
            int row = (int)(idx >> 12);
            int col = (int)(idx & 4095);
            ushort4 o;
            if (row < HIDDEN) {
                float4 f = *(const float4*)(wout_src + (long)row * QD + col);
                o.x = f2bf(f.x); o.y = f2bf(f.y); o.z = f2bf(f.z); o.w = f2bf(f.w);
            } else {
                o.x = 0; o.y = 0; o.z = 0; o.w = 0;
            }
            ((ushort4*)wout_dst)[i] = o;
        }
        return;
    }

    extern __shared__ u16 smem[];
    u16* const smA = smem;                  // [3][256][64] bf16 (32 KB/slot)
    u16* const smB = smem + 3 * 256 * 64;   // byte 98304, [2][256][64]
    const int lane = tid & 63;
    const int wv   = tid >> 6;              // wave 0..7
    const int wm2  = wv >> 1;               // 0..3 (M quad, 64 rows)
    const int wn2  = wv & 1;                // 0..1 (N half, 128 cols)
    const long m0  = (long)blockIdx.y * 256;
    const long n0  = (long)blockIdx.x * 256;
    const int kbase = blockIdx.z * ksplit;
    int krem = K - kbase; if (krem > ksplit) krem = ksplit;
    const int NT   = krem >> 6;             // K-tiles of 64
    u16* C = C0 + (size_t)blockIdx.z * ((size_t)TTOK * N);

    const int srow = tid >> 3;                              // 0..63
    const int sg8  = ((tid & 7) ^ (srow & 7)) << 3;         // src elem offset
    const int fr   = lane & 15;
    const int off0 = ((lane >> 4) << 4) ^ ((lane & 7) << 4);
    const int off1 = off0 ^ 64;
    const char* aR = (const char*)smA + (wm2 * 64  + fr) * 128;
    const char* bR = (const char*)smB + (wn2 * 128 + fr) * 128;

    f32x4 acc[4][8];
    #pragma unroll
    for (int i = 0; i < 4; ++i)
        #pragma unroll
        for (int j = 0; j < 8; ++j) acc[i][j] = f32x4{0.f, 0.f, 0.f, 0.f};

    const u16* Asrc = A + (m0 + srow) * (long)K + kbase + sg8;
    auto stageA = [&](int t, int slot) {
        char* dst = (char*)smA + slot * 32768 + wv * 1024;
        const u16* src = Asrc + t * 64;
        #pragma unroll
        for (int hj = 0; hj < 4; ++hj)
            glds16(src + (size_t)(hj * 64) * K, dst + hj * 8192);
    };
    auto stageBh = [&](int t, int h) {
        char* dst = (char*)smB + (t & 1) * 32768 + (h * 128 + wv * 8) * 128;
        #pragma unroll
        for (int j = 0; j < 2; ++j) {
            long r = n0 + h * 128 + j * 64 + srow;
            if (r > blimit) r = blimit;
            glds16(B + (size_t)r * K + kbase + t * 64 + sg8, dst + j * 8192);
        }
    };

    bf16x8 aq[4][2], bqE[2][2], bqO[2][2];

    // prologue: B(0) both halves, A(0)->slot0, A(1)->slot1 (12 loads).
    // VMW(4) waits oldest 8 -> B(0),A(0) landed; A(1) may be outstanding.
    stageBh(0, 0); stageBh(0, 1);
    stageA(0, 0);
    if (NT > 1) { stageA(1, 1); VMW(4); }
    else        { VMW(0); }
    BARB();
    READ_BQ(bqE, bR, 0);      // B(0).q0  (consumed ph1(0), in-wave lgkm)
    READ_AQ(aR);              // A(0)

    int sA = 0;
    for (int t = 0; t < NT; ++t) {
        int sA1 = sA + 1; if (sA1 == 3) sA1 = 0;
        int sA2 = sA1 + 1; if (sA2 == 3) sA2 = 0;
        const char* bS  = bR + (t & 1) * 32768;
        const char* bS1 = bR + ((t + 1) & 1) * 32768;
        // ph1: read q1->O; stage B(t+1) both + A(t+2); MFMA q0
        READ_BQ(bqO, bS, 1);
        if (t + 1 < NT) { stageBh(t + 1, 0); stageBh(t + 1, 1); }
        if (t + 2 < NT) stageA(t + 2, sA2);
        MFMA_N(0, bqE);
        SB0();
        // ph2: read q2->E; MFMA q1
        READ_BQ(bqE, bS, 2);
        MFMA_N(1, bqO);
        SB0();
        // ph3: read q3->O; MFMA q2; counted checkpoint + barrier
        READ_BQ(bqO, bS, 3);
        MFMA_N(2, bqE);
        if (t + 2 < NT)      VMW(4);
        else if (t + 1 < NT) VMW(0);
        BARB();
        // ph4: read B(t+1).q0->E; MFMA q3; read aq(t+1); barrier (NO lgkm drain:
        // ph4 reads retire via ph1(t+1)'s MFMA per-wave lgkm; slot safety above)
        if (t + 1 < NT) READ_BQ(bqE, bS1, 0);
        MFMA_N(3, bqO);
        if (t + 1 < NT) READ_AQ(aR + sA1 * 32768);
        BARB();
        sA = sA1;
    }

    // epilogue: C/D layout col=lane&15, row=(lane>>4)*4+reg  [m89-verified]
    const int cr = (lane >> 4) * 4;
    const int cc = lane & 15;
    #pragma unroll
    for (int nf = 0; nf < 8; ++nf) {
        long col = n0 + wn2 * 128 + nf * 16 + cc;
        if (col < colmax) {
            #pragma unroll
            for (int mi = 0; mi < 4; ++mi) {
                long row = m0 + wm2 * 64 + mi * 16 + cr;
                #pragma unroll
                for (int r2 = 0; r2 < 4; ++r2)
                    C[(row + r2) * (long)N + col] = f2bf(acc[mi][nf][r2]);
            }
        }
    }
}

// -- R12 GEMM2: 256x192 3-quad, same relaxed sync (3 A-slots, no lgkm drain) ----
// ph1: read q1->S0; stage B3(t+1)+A(t+2); MFMA q0(S2)
// ph2: read q2->S1; MFMA q1(S0)
// ph3: MFMA q2(S1); VMW(4); BARB      [outstanding: A(t+1)4+B(t+1)3+A(t+2)4=11]
// ph4: read q0(t+1)->S2 + aq(t+1); BARB
// LDS 144 KB: A[3][256][64] (96K) + B[2][192][64] (48K).
__global__ __launch_bounds__(512, 2) void gemm_bt_3q(const u16* __restrict__ A,
                                                     const u16* __restrict__ B,
                                                     u16* __restrict__ C0,
                                                     int N, int K, int ksplit,
                                                     int blimit) {
    extern __shared__ u16 smem[];
    u16* const smA = smem;                  // [3][256][64] (32 KB/slot)
    u16* const smB = smem + 3 * 256 * 64;   // byte 98304, [2][192][64] (24 KB/slot)
    const int tid  = threadIdx.x;
    const int lane = tid & 63;
    const int wv   = tid >> 6;
    const int wm2  = wv >> 1;
    const int wn2  = wv & 1;
    const long m0  = (long)blockIdx.y * 256;
    const long n0  = (long)blockIdx.x * 192;
    const int kbase = blockIdx.z * ksplit;
    int krem = K - kbase; if (krem > ksplit) krem = ksplit;
    const int NT   = krem >> 6;
    u16* C = C0 + (size_t)blockIdx.z * ((size_t)TTOK * N);

    const int srow = tid >> 3;
    const int sg8  = ((tid & 7) ^ (srow & 7)) << 3;
    const int fr   = lane & 15;
    const int off0 = ((lane >> 4) << 4) ^ ((lane & 7) << 4);
    const int off1 = off0 ^ 64;
    const char* aR = (const char*)smA + (wm2 * 64 + fr) * 128;
    const char* bR = (const char*)smB + (wn2 * 96 + fr) * 128;

    f32x4 acc[4][6];
    #pragma unroll
    for (int i = 0; i < 4; ++i)
        #pragma unroll
        for (int j = 0; j < 6; ++j) acc[i][j] = f32x4{0.f, 0.f, 0.f, 0.f};

    const u16* Asrc = A + (m0 + srow) * (long)K + kbase + sg8;
    auto stageA = [&](int t, int slot) {
        char* dst = (char*)smA + slot * 32768 + wv * 1024;
        const u16* src = Asrc + t * 64;
        #pragma unroll
        for (int hj = 0; hj < 4; ++hj)
            glds16(src + (size_t)(hj * 64) * K, dst + hj * 8192);
    };
    auto stageB3 = [&](int t) {
        char* base = (char*)smB + (t & 1) * 24576;
        #pragma unroll
        for (int j = 0; j < 3; ++j) {
            long r = n0 + j * 64 + srow;
            if (r > blimit) r = blimit;
            glds16(B + (size_t)r * K + kbase + t * 64 + sg8,
                   base + (j * 64 + wv * 8) * 128);
        }
    };

    bf16x8 aq[4][2], s0[2][2], s1[2][2], s2[2][2];

    // prologue: B(0)x3, A(0)->slot0, A(1)->slot1 (11 loads); VMW(4) leaves A(1).
    stageB3(0);
    stageA(0, 0);
    if (NT > 1) { stageA(1, 1); VMW(4); }
    else        { VMW(0); }
    BARB();
    READ_BQ(s2, bR, 0);
    READ_AQ(aR);

    int sA = 0;
    for (int t = 0; t < NT; ++t) {
        int sA1 = sA + 1; if (sA1 == 3) sA1 = 0;
        int sA2 = sA1 + 1; if (sA2 == 3) sA2 = 0;
        const char* bS  = bR + (t & 1) * 24576;
        const char* bS1 = bR + ((t + 1) & 1) * 24576;
        // ph1
        READ_BQ(s0, bS, 1);
        if (t + 1 < NT) stageB3(t + 1);
        if (t + 2 < NT) stageA(t + 2, sA2);
        MFMA_N(0, s2);
        SB0();
        // ph2
        READ_BQ(s1, bS, 2);
        MFMA_N(1, s0);
        SB0();
        // ph3
        MFMA_N(2, s1);
        if (t + 2 < NT)      VMW(4);
        else if (t + 1 < NT) VMW(0);
        BARB();
        // ph4
        if (t + 1 < NT) { READ_BQ(s2, bS1, 0); READ_AQ(aR + sA1 * 32768); }
        BARB();
        sA = sA1;
    }

    const int cr = (lane >> 4) * 4;
    const int cc = lane & 15;
    #pragma unroll
    for (int nf = 0; nf < 6; ++nf) {
        long col = n0 + wn2 * 96 + nf * 16 + cc;
        #pragma unroll
        for (int mi = 0; mi < 4; ++mi) {
            long row = m0 + wm2 * 64 + mi * 16 + cr;
            #pragma unroll
            for (int r2 = 0; r2 < 4; ++r2)
                C[(row + r2) * (long)N + col] = f2bf(acc[mi][nf][r2]);
        }
    }
}

// ------- RoPE (YaRN), consumes GEMM1 output + bias (R10, restored) -------------
__global__ __launch_bounds__(256) void rope_kernel(const u16* __restrict__ p1,
                                                   const float* __restrict__ b_qkv,
                                                   u16* __restrict__ qr,
                                                   u16* __restrict__ kr,
                                                   u16* __restrict__ vr,
                                                   int nsplit) {
    const int t = blockIdx.x;
    const int tid = threadIdx.x;
    __shared__ float cs[32], sn[32];
    if (tid < 32) {
        float fi = (float)tid;
        float freq   = exp2f(17.1946032f * (fi * (1.0f / 32.0f)));   // 150000^(i/32)
        float interp = 1.0f / (32.0f * freq);
        float extra  = 1.0f / freq;
        float ramp   = (fi - 8.0927802f) * (1.0f / (17.3980220f - 8.0927802f));
        float rc     = fminf(fmaxf(ramp, 0.0f), 1.0f);               // = 1 - mask
        float invf   = interp * rc + extra * (1.0f - rc);
        float ang    = (float)t * invf;
        cs[tid] = cosf(ang) * 1.3465736f;                            // * concentration
        sn[tid] = sinf(ang) * 1.3465736f;
    }
    __syncthreads();
    const u16* rowA = p1 + (long)t * QKVD;
    auto pair = [&](int col) -> float2 {
        float2 bb = *(const float2*)(b_qkv + col);
        float a = bb.x, b = bb.y;
        for (int s = 0; s < nsplit; ++s) {
            u32 u = *(const u32*)(rowA + (size_t)s * TTOK * QKVD + col);
            a += bflo(u); b += bfhi(u);
        }
        return make_float2(a, b);
    };
    // Q: 64 heads x 32 pairs
    for (int p = tid; p < 2048; p += 256) {
        int hd2 = p >> 5, i = p & 31;
        float2 ab = pair(hd2 * 64 + 2 * i);
        float o1 = ab.x * cs[i] - ab.y * sn[i];
        float o2 = ab.y * cs[i] + ab.x * sn[i];
        *(u32*)(qr + (long)t * QD + hd2 * 64 + 2 * i) = (u32)f2bf(o1) | ((u32)f2bf(o2) << 16);
    }
    // K: 8 heads x 32 pairs == 256 threads; head-major layout [kv][t][64]
    {
        int kv = tid >> 5, i = tid & 31;
        float2 ab = pair(QD + kv * 64 + 2 * i);
        float o1 = ab.x * cs[i] - ab.y * sn[i];
        float o2 = ab.y * cs[i] + ab.x * sn[i];
        *(u32*)(kr + ((long)kv * TTOK + t) * HD + 2 * i) = (u32)f2bf(o1) | ((u32)f2bf(o2) << 16);
    }
    // V: 8 heads x 64 = 256 u32; head-major [kv][t][64]
    {
        int kv = tid >> 5, d2 = tid & 31;
        float2 ab = pair(QD + 512 + kv * 64 + 2 * d2);
        *(u32*)(vr + ((long)kv * TTOK + t) * HD + 2 * d2) = (u32)f2bf(ab.x) | ((u32)f2bf(ab.y) << 16);
    }
}

// -------- attn (R9, restored): merged-z (8 q-heads/block), packed-u32 V^T ------
__global__ __launch_bounds__(512, 1) void attn_kernel(const u16* __restrict__ qr,
                                                      const u16* __restrict__ kr,
                                                      const u16* __restrict__ vr,
                                                      const float* __restrict__ sinks,
                                                      u16* __restrict__ o) {
    const int t0  = blockIdx.x * 16;
    const int h   = blockIdx.y;
    const int tid = threadIdx.x;
    const int lane = tid & 63, wv = tid >> 6;    // wv = q-head 0..7
    extern __shared__ __align__(16) u16 asmem[];
    u16* const ks = asmem;                        // [144][72]
    u16* const Vt = asmem + 144 * 72;             // [64][168], cols 144..159 zero
    u16* const Pb = asmem + 144 * 72 + 64 * 168;  // [8][16][168], cols 144..159 zero
    const u16* kb = kr + (long)h * TTOK * HD;
    const u16* vb = vr + (long)h * TTOK * HD;

    #pragma unroll
    for (int i = 0; i < 3; ++i) {
        int idx = i * 512 + tid;
        if (idx < 144 * 8) {
            int rr = idx >> 3, c = idx & 7;
            int tk = t0 - 128 + rr;
            int tks = tk < 0 ? 0 : tk;
            *(uint4*)(ks + rr * 72 + c * 8) = *(const uint4*)(kb + (long)tks * HD + c * 8);
        }
    }
    if (tid < 288) {
        const int kp = tid >> 2, c2 = tid & 3;
        const int k0 = kp * 2;
        int tk0 = t0 - 128 + k0;     tk0 = tk0 < 0 ? 0 : tk0;
        int tk1 = t0 - 128 + k0 + 1; tk1 = tk1 < 0 ? 0 : tk1;
        uint4 a0 = *(const uint4*)(vb + (long)tk0 * HD + c2 * 16);
        uint4 a1 = *(const uint4*)(vb + (long)tk0 * HD + c2 * 16 + 8);
        uint4 b0 = *(const uint4*)(vb + (long)tk1 * HD + c2 * 16);
        uint4 b1 = *(const uint4*)(vb + (long)tk1 * HD + c2 * 16 + 8);
        u32 wa[8] = {a0.x, a0.y, a0.z, a0.w, a1.x, a1.y, a1.z, a1.w};
        u32 wb[8] = {b0.x, b0.y, b0.z, b0.w, b1.x, b1.y, b1.z, b1.w};
        u16* vrow = Vt + c2 * 16 * 168 + k0;
        if (c2 & 2) {
            #pragma unroll
            for (int dd = 0; dd < 16; ++dd) {
                int d = (dd + 4) & 15;
                u32 oo = (d & 1) ? ((wa[d >> 1] >> 16) | (wb[d >> 1] & 0xffff0000u))
                                 : ((wa[d >> 1] & 0xffffu) | (wb[d >> 1] << 16));
                *(u32*)(vrow + d * 168) = oo;
            }
        } else {
            #pragma unroll
            for (int d = 0; d < 16; ++d) {
                u32 oo = (d & 1) ? ((wa[d >> 1] >> 16) | (wb[d >> 1] & 0xffff0000u))
                                 : ((wa[d >> 1] & 0xffffu) | (wb[d >> 1] << 16));
                *(u32*)(vrow + d * 168) = oo;
            }
        }
    }
    if (tid < 128) {
        *(uint4*)(Vt + (tid >> 1) * 168 + 144 + (tid & 1) * 8) = uint4{0, 0, 0, 0};
    }
    if (lane < 32) {
        *(uint4*)(Pb + wv * 16 * 168 + (lane >> 1) * 168 + 144 + (lane & 1) * 8) = uint4{0, 0, 0, 0};
    }
    __syncthreads();

    const int head = h * QMULT + wv;
    const int fr = lane & 15, fk = (lane >> 4) * 8;
    const int cr = (lane >> 4) * 4;
    u16* const Pw = Pb + wv * 16 * 168;

    const u16* qrow = qr + (long)(t0 + fr) * QD + head * HD;
    bf16x8 qf0 = *(const bf16x8*)(qrow + fk);
    bf16x8 qf1 = *(const bf16x8*)(qrow + 32 + fk);

    const int kmin = 128 - t0;
    float lsum[4] = {0.f, 0.f, 0.f, 0.f};

    for (int nt = 0; nt < 9; ++nt) {
        bf16x8 b0 = *(const bf16x8*)(ks + (nt * 16 + fr) * 72 + fk);
        bf16x8 b1 = *(const bf16x8*)(ks + (nt * 16 + fr) * 72 + 32 + fk);
        f32x4 s = f32x4{0.f, 0.f, 0.f, 0.f};
        s = __builtin_amdgcn_mfma_f32_16x16x32_bf16(qf0, b0, s, 0, 0, 0);
        s = __builtin_amdgcn_mfma_f32_16x16x32_bf16(qf1, b1, s, 0, 0, 0);
        const int kk = nt * 16 + fr;
        #pragma unroll
        for (int r = 0; r < 4; ++r) {
            int row = cr + r;
            bool valid = (kk >= row) && (kk <= row + 128) && (kk >= kmin);
            float p = valid ? __expf(s[r] * 0.125f) : 0.0f;
            lsum[r] += p;
            Pw[row * 168 + kk] = f2bf(p);
        }
    }

    f32x4 oacc[4];
    #pragma unroll
    for (int dt = 0; dt < 4; ++dt) oacc[dt] = f32x4{0.f, 0.f, 0.f, 0.f};
    #pragma unroll
    for (int k5 = 0; k5 < 5; ++k5) {
        const int k0 = k5 * 32;
        bf16x8 pa = *(const bf16x8*)(Pw + fr * 168 + k0 + fk);
        #pragma unroll
        for (int dt = 0; dt < 4; ++dt) {
            bf16x8 vf = *(const bf16x8*)(Vt + (dt * 16 + fr) * 168 + k0 + fk);
            oacc[dt] = __builtin_amdgcn_mfma_f32_16x16x32_bf16(pa, vf, oacc[dt], 0, 0, 0);
        }
    }

    #pragma unroll
    for (int r = 0; r < 4; ++r) {
        float v = lsum[r];
        v += __shfl_xor(v, 1);
        v += __shfl_xor(v, 2);
        v += __shfl_xor(v, 4);
        v += __shfl_xor(v, 8);
        lsum[r] = v;
    }
    const float sk = exp2f(sinks[head]);
    float inv[4];
    #pragma unroll
    for (int r = 0; r < 4; ++r) inv[r] = 1.0f / (lsum[r] + sk);

    #pragma unroll
    for (int dt = 0; dt < 4; ++dt) {
        #pragma unroll
        for (int r = 0; r < 4; ++r) {
            o[(long)(t0 + cr + r) * QD + head * HD + dt * 16 + fr] = f2bf(oacc[dt][r] * inv[r]);
        }
    }
}

// ---------------- reduce GEMM2 partials + bias + residual -> out ----------------
__global__ __launch_bounds__(256) void reduce2_kernel(const u16* __restrict__ p2a,
                                                      const u16* __restrict__ p2b,
                                                      const float* __restrict__ x,
                                                      const float* __restrict__ b_out,
                                                      float* __restrict__ out) {
    const int row = blockIdx.y;
    const int c4 = blockIdx.x * 256 + threadIdx.x;   // float4 index within row
    if (c4 >= 720) return;
    const int col = c4 * 4;
    ushort4 ua = *(const ushort4*)(p2a + (long)row * NPAD + col);
    ushort4 ub = *(const ushort4*)(p2b + (long)row * NPAD + col);
    float4 xv = *(const float4*)(x + (long)row * HIDDEN + col);
    float4 bv = *(const float4*)(b_out + col);
    float4 o;
    o.x = xv.x + bv.x + __uint_as_float((u32)ua.x << 16) + __uint_as_float((u32)ub.x << 16);
    o.y = xv.y + bv.y + __uint_as_float((u32)ua.y << 16) + __uint_as_float((u32)ub.y << 16);
    o.z = xv.z + bv.z + __uint_as_float((u32)ua.z << 16) + __uint_as_float((u32)ub.z << 16);
    o.w = xv.w + bv.w + __uint_as_float((u32)ua.w << 16) + __uint_as_float((u32)ub.w << 16);
    *(float4*)(out + (long)row * HIDDEN + col) = o;
}

// ---------------- launcher ----------------
extern "C" void kernel_launch(void* const* d_in, const int* in_sizes, int n_in,
                              void* d_out, int out_size, void* d_ws, size_t ws_size,
                              hipStream_t stream) {
    const float* x      = (const float*)d_in[0];
    const float* nscale = (const float*)d_in[1];
    const float* w_qkv  = (const float*)d_in[2];
    const float* b_qkv  = (const float*)d_in[3];
    const float* sinks  = (const float*)d_in[4];
    const float* w_out  = (const float*)d_in[5];
    const float* b_out  = (const float*)d_in[6];
    float* out = (float*)d_out;

    static int smem_set = 0;
    if (!smem_set) {
        hipFuncSetAttribute((const void*)gemm_bt_8ph,
                            hipFuncAttributeMaxDynamicSharedMemorySize, 163840);
        hipFuncSetAttribute((const void*)gemm_bt_3q,
                            hipFuncAttributeMaxDynamicSharedMemorySize, 147456);
        hipFuncSetAttribute((const void*)attn_kernel,
                            hipFuncAttributeMaxDynamicSharedMemorySize, 85248);
        smem_set = 1;
    }

    char* ws = (char*)d_ws;
    size_t off = 0;
    auto alloc = [&](size_t bytes) { void* p = ws + off; off += (bytes + 255) & ~(size_t)255; return p; };
    const size_t p1_bytes  = (size_t)TTOK * QKVD * 2;          // 21.0 MB (GEMM1 out)
    const size_t p2_bytes  = (size_t)2 * TTOK * NPAD * 2;      // 25.2 MB (GEMM2 partials)
    u16* wqkv_bf = (u16*)alloc((size_t)QKVD * HIDDEN * 2);     // 29.5 MB
    u16* wout_bf = (u16*)alloc((size_t)NPAD * QD * 2);         // 25.2 MB
    u16* h       = (u16*)alloc((size_t)TTOK * HIDDEN * 2);     // 11.8 MB
    u16* p1      = (u16*)alloc(p1_bytes > p2_bytes ? p1_bytes : p2_bytes);
    u16* qrot    = (u16*)alloc((size_t)TTOK * QD * 2);         // 16.8 MB
    // aliases (dead-after analysis):
    u16* attn = wqkv_bf;                       // wqkv_bf dead after gemm1 (16.8 MB)
    u16* krot = wqkv_bf + (size_t)TTOK * QD;   // wqkv tail: +2.1 MB
    u16* vrot = krot + (size_t)NKV * TTOK * HD;// +2.1 MB (total 21.0 <= 29.5 OK)
    u16* p2   = p1;                            // p1 dead after rope; sized above

    prep_kernel<<<PREP_QKV_BLOCKS + PREP_RMS_BLOCKS, 256, 0, stream>>>(
        w_qkv, wqkv_bf, x, nscale, h);
    // GEMM1: full-K, 160 gemm blocks + 96 working filler blocks (z=1; rest exit)
    gemm_bt_8ph<<<dim3(QKVD / 256, TTOK / 256, 2), 512, 163840, stream>>>(
        h, wqkv_bf, p1, QKVD, HIDDEN, HIDDEN, QKVD - 1, QKVD, 1, 96, w_out, wout_bf);
    rope_kernel<<<TTOK, 256, 0, stream>>>(p1, b_qkv, qrot, krot, vrot, 1);
    // attn: merged-z, 128x8 = 1024 blocks x 512 thr, 85 KB dynamic LDS
    attn_kernel<<<dim3(TTOK / 16, NKV), 512, 85248, stream>>>(
        qrot, krot, vrot, sinks, attn);
    // GEMM2: 256x192 tiles, split-K z=2 -> 16x8x2 = 256 blocks (full fill)
    gemm_bt_3q<<<dim3(NPAD / 192, TTOK / 256, 2), 512, 147456, stream>>>(
        attn, wout_bf, p2, NPAD, QD, QD / 2, NPAD - 1);
    reduce2_kernel<<<dim3(3, TTOK), 256, 0, stream>>>(
        p2, p2 + (size_t)TTOK * NPAD, x, b_out, out);
}

// Round 13
// 316.650 us; speedup vs baseline: 1.0300x; 1.0079x over previous
//
#include <hip/hip_runtime.h>
#include <math.h>

typedef unsigned short u16;
typedef unsigned int   u32;
using f32x4  = __attribute__((ext_vector_type(4))) float;
using bf16x8 = __attribute__((ext_vector_type(8))) __bf16;

#define HIDDEN   2880
#define QKVD     5120
#define QD       4096
#define TTOK     2048
#define NKV      8
#define QMULT    8
#define HD       64
#define NPAD     3072   // w_out rows padded to 16*192 -> GEMM2 grid 16x8x2 = 256 blocks

#define PREP_QKV_BLOCKS  14400   // QKVD*HIDDEN/4/256
#define PREP_RMS_BLOCKS  2048

static __device__ __forceinline__ float bflo(u32 u){ return __uint_as_float(u << 16); }
static __device__ __forceinline__ float bfhi(u32 u){ return __uint_as_float(u & 0xffff0000u); }
static __device__ __forceinline__ u16 f2bf(float f){
    u32 u = __float_as_uint(f);
    u32 r = (u + 0x7fffu + ((u >> 16) & 1u)) >> 16;
    return (u16)r;
}

static __device__ __forceinline__ void glds16(const void* g, void* l) {
    __builtin_amdgcn_global_load_lds(
        (__attribute__((address_space(1))) void*)g,
        (__attribute__((address_space(3))) void*)l,
        16, 0, 0);
}

// Mechanics: raw s_barrier (no waitcnt drain), counted vmcnt, sched_barrier pins.
#define SB0()   __builtin_amdgcn_sched_barrier(0)
#define BARB()  do { SB0(); __builtin_amdgcn_s_barrier(); SB0(); } while (0)
#define VMW(N)  do { SB0(); asm volatile("s_waitcnt vmcnt(" #N ")"); SB0(); } while (0)

// ---------------- fused prep: w_qkv cvt | rmsnorm ----------------
__global__ __launch_bounds__(256) void prep_kernel(const float* __restrict__ w_qkv,
                                                   u16* __restrict__ wqkv_bf,
                                                   const float* __restrict__ x,
                                                   const float* __restrict__ scale,
                                                   u16* __restrict__ h) {
    const int b = blockIdx.x;
    const int tid = threadIdx.x;
    if (b < PREP_QKV_BLOCKS) {
        int i = b * 256 + tid;
        float4 f = ((const float4*)w_qkv)[i];
        ushort4 o;
        o.x = f2bf(f.x); o.y = f2bf(f.y); o.z = f2bf(f.z); o.w = f2bf(f.w);
        ((ushort4*)wqkv_bf)[i] = o;
    } else {
        const int t = b - PREP_QKV_BLOCKS;
        const float4* xr = (const float4*)(x + (long)t * HIDDEN);
        float4 v[3];
        float ss = 0.f;
        #pragma unroll
        for (int it = 0; it < 3; ++it) {
            int i4 = tid + it * 256;
            if (i4 < 720) {
                v[it] = xr[i4];
                ss += v[it].x*v[it].x + v[it].y*v[it].y + v[it].z*v[it].z + v[it].w*v[it].w;
            }
        }
        #pragma unroll
        for (int off = 32; off > 0; off >>= 1) ss += __shfl_down(ss, off);
        __shared__ float red[4];
        if ((tid & 63) == 0) red[tid >> 6] = ss;
        __syncthreads();
        float tot = red[0] + red[1] + red[2] + red[3];
        float rr = rsqrtf(tot * (1.0f / HIDDEN) + 1e-5f);
        ushort4* hr = (ushort4*)(h + (long)t * HIDDEN);
        #pragma unroll
        for (int it = 0; it < 3; ++it) {
            int i4 = tid + it * 256;
            if (i4 < 720) {
                float4 s4 = ((const float4*)scale)[i4];
                ushort4 o;
                o.x = f2bf(v[it].x * rr * s4.x);
                o.y = f2bf(v[it].y * rr * s4.y);
                o.z = f2bf(v[it].z * rr * s4.z);
                o.w = f2bf(v[it].w * rr * s4.w);
                hr[i4] = o;
            }
        }
    }
}

// -- GEMM1 (R12, frozen): phase-ahead 256x256/BK=64, 3 A-slots, 2 barriers/tile.
// Four structurally distinct schedules all measured 4450-4880 cy/tile (R6/R10/
// R12 = 83.7-84.0us) -> practical plateau; 62.5% fill repaid by free w_out
// filler on the 96 idle CUs.

#define READ_BQ(SET, BASE, NQ) do { \
    SET[0][0] = *(const bf16x8*)((BASE) + (2*(NQ)+0)*2048 + off0); \
    SET[0][1] = *(const bf16x8*)((BASE) + (2*(NQ)+0)*2048 + off1); \
    SET[1][0] = *(const bf16x8*)((BASE) + (2*(NQ)+1)*2048 + off0); \
    SET[1][1] = *(const bf16x8*)((BASE) + (2*(NQ)+1)*2048 + off1); \
} while (0)

#define READ_AQ(BASE) do { \
    _Pragma("unroll") \
    for (int mi_ = 0; mi_ < 4; ++mi_) { \
        aq[mi_][0] = *(const bf16x8*)((BASE) + mi_*2048 + off0); \
        aq[mi_][1] = *(const bf16x8*)((BASE) + mi_*2048 + off1); \
    } \
} while (0)

#define MFMA_N(NQ, SET) do { \
    __builtin_amdgcn_s_setprio(1); \
    _Pragma("unroll") \
    for (int mi_ = 0; mi_ < 4; ++mi_) { \
        _Pragma("unroll") \
        for (int j_ = 0; j_ < 2; ++j_) { \
            acc[mi_][2*(NQ)+j_] = __builtin_amdgcn_mfma_f32_16x16x32_bf16(aq[mi_][0], SET[j_][0], acc[mi_][2*(NQ)+j_], 0, 0, 0); \
            acc[mi_][2*(NQ)+j_] = __builtin_amdgcn_mfma_f32_16x16x32_bf16(aq[mi_][1], SET[j_][1], acc[mi_][2*(NQ)+j_], 0, 0, 0); \
        } \
    } \
    __builtin_amdgcn_s_setprio(0); \
} while (0)

__global__ __launch_bounds__(512, 2) void gemm_bt_8ph(const u16* __restrict__ A,
                                                      const u16* __restrict__ B,
                                                      u16* __restrict__ C0,
                                                      int N, int K, int ksplit,
                                                      int blimit, int colmax,
                                                      int nz_gemm, int nfill,
                                                      const float* __restrict__ wout_src,
                                                      u16* __restrict__ wout_dst) {
    const int tid  = threadIdx.x;

    if ((int)blockIdx.z >= nz_gemm) {
        long bidx = (long)blockIdx.y * gridDim.x + blockIdx.x;
        if (bidx >= nfill) return;
        long i = bidx * 512 + tid;
        const long tot = (long)NPAD * QD / 4;
        const long stride = (long)nfill * 512;
        for (; i < tot; i += stride) {
            long idx = i * 4;
            int row = (int)(idx >> 12);
            int col = (int)(idx & 4095);
            ushort4 o;
            if (row < HIDDEN) {
                float4 f = *(const float4*)(wout_src + (long)row * QD + col);
                o.x = f2bf(f.x); o.y = f2bf(f.y); o.z = f2bf(f.z); o.w = f2bf(f.w);
            } else {
                o.x = 0; o.y = 0; o.z = 0; o.w = 0;
            }
            ((ushort4*)wout_dst)[i] = o;
        }
        return;
    }

    extern __shared__ u16 smem[];
    u16* const smA = smem;                  // [3][256][64] bf16 (32 KB/slot)
    u16* const smB = smem + 3 * 256 * 64;   // byte 98304, [2][256][64]
    const int lane = tid & 63;
    const int wv   = tid >> 6;
    const int wm2  = wv >> 1;
    const int wn2  = wv & 1;
    const long m0  = (long)blockIdx.y * 256;
    const long n0  = (long)blockIdx.x * 256;
    const int kbase = blockIdx.z * ksplit;
    int krem = K - kbase; if (krem > ksplit) krem = ksplit;
    const int NT   = krem >> 6;
    u16* C = C0 + (size_t)blockIdx.z * ((size_t)TTOK * N);

    const int srow = tid >> 3;
    const int sg8  = ((tid & 7) ^ (srow & 7)) << 3;
    const int fr   = lane & 15;
    const int off0 = ((lane >> 4) << 4) ^ ((lane & 7) << 4);
    const int off1 = off0 ^ 64;
    const char* aR = (const char*)smA + (wm2 * 64  + fr) * 128;
    const char* bR = (const char*)smB + (wn2 * 128 + fr) * 128;

    f32x4 acc[4][8];
    #pragma unroll
    for (int i = 0; i < 4; ++i)
        #pragma unroll
        for (int j = 0; j < 8; ++j) acc[i][j] = f32x4{0.f, 0.f, 0.f, 0.f};

    const u16* Asrc = A + (m0 + srow) * (long)K + kbase + sg8;
    auto stageA = [&](int t, int slot) {
        char* dst = (char*)smA + slot * 32768 + wv * 1024;
        const u16* src = Asrc + t * 64;
        #pragma unroll
        for (int hj = 0; hj < 4; ++hj)
            glds16(src + (size_t)(hj * 64) * K, dst + hj * 8192);
    };
    auto stageBh = [&](int t, int h) {
        char* dst = (char*)smB + (t & 1) * 32768 + (h * 128 + wv * 8) * 128;
        #pragma unroll
        for (int j = 0; j < 2; ++j) {
            long r = n0 + h * 128 + j * 64 + srow;
            if (r > blimit) r = blimit;
            glds16(B + (size_t)r * K + kbase + t * 64 + sg8, dst + j * 8192);
        }
    };

    bf16x8 aq[4][2], bqE[2][2], bqO[2][2];

    stageBh(0, 0); stageBh(0, 1);
    stageA(0, 0);
    if (NT > 1) { stageA(1, 1); VMW(4); }
    else        { VMW(0); }
    BARB();
    READ_BQ(bqE, bR, 0);
    READ_AQ(aR);

    int sA = 0;
    for (int t = 0; t < NT; ++t) {
        int sA1 = sA + 1; if (sA1 == 3) sA1 = 0;
        int sA2 = sA1 + 1; if (sA2 == 3) sA2 = 0;
        const char* bS  = bR + (t & 1) * 32768;
        const char* bS1 = bR + ((t + 1) & 1) * 32768;
        READ_BQ(bqO, bS, 1);
        if (t + 1 < NT) { stageBh(t + 1, 0); stageBh(t + 1, 1); }
        if (t + 2 < NT) stageA(t + 2, sA2);
        MFMA_N(0, bqE);
        SB0();
        READ_BQ(bqE, bS, 2);
        MFMA_N(1, bqO);
        SB0();
        READ_BQ(bqO, bS, 3);
        MFMA_N(2, bqE);
        if (t + 2 < NT)      VMW(4);
        else if (t + 1 < NT) VMW(0);
        BARB();
        if (t + 1 < NT) READ_BQ(bqE, bS1, 0);
        MFMA_N(3, bqO);
        if (t + 1 < NT) READ_AQ(aR + sA1 * 32768);
        BARB();
        sA = sA1;
    }

    const int cr = (lane >> 4) * 4;
    const int cc = lane & 15;
    #pragma unroll
    for (int nf = 0; nf < 8; ++nf) {
        long col = n0 + wn2 * 128 + nf * 16 + cc;
        if (col < colmax) {
            #pragma unroll
            for (int mi = 0; mi < 4; ++mi) {
                long row = m0 + wm2 * 64 + mi * 16 + cr;
                #pragma unroll
                for (int r2 = 0; r2 < 4; ++r2)
                    C[(row + r2) * (long)N + col] = f2bf(acc[mi][nf][r2]);
            }
        }
    }
}

// -- GEMM2 (R12, frozen): 256x192 3-quad, full-fill 16x8x2=256, 3 A-slots ------
__global__ __launch_bounds__(512, 2) void gemm_bt_3q(const u16* __restrict__ A,
                                                     const u16* __restrict__ B,
                                                     u16* __restrict__ C0,
                                                     int N, int K, int ksplit,
                                                     int blimit) {
    extern __shared__ u16 smem[];
    u16* const smA = smem;                  // [3][256][64] (32 KB/slot)
    u16* const smB = smem + 3 * 256 * 64;   // [2][192][64] (24 KB/slot)
    const int tid  = threadIdx.x;
    const int lane = tid & 63;
    const int wv   = tid >> 6;
    const int wm2  = wv >> 1;
    const int wn2  = wv & 1;
    const long m0  = (long)blockIdx.y * 256;
    const long n0  = (long)blockIdx.x * 192;
    const int kbase = blockIdx.z * ksplit;
    int krem = K - kbase; if (krem > ksplit) krem = ksplit;
    const int NT   = krem >> 6;
    u16* C = C0 + (size_t)blockIdx.z * ((size_t)TTOK * N);

    const int srow = tid >> 3;
    const int sg8  = ((tid & 7) ^ (srow & 7)) << 3;
    const int fr   = lane & 15;
    const int off0 = ((lane >> 4) << 4) ^ ((lane & 7) << 4);
    const int off1 = off0 ^ 64;
    const char* aR = (const char*)smA + (wm2 * 64 + fr) * 128;
    const char* bR = (const char*)smB + (wn2 * 96 + fr) * 128;

    f32x4 acc[4][6];
    #pragma unroll
    for (int i = 0; i < 4; ++i)
        #pragma unroll
        for (int j = 0; j < 6; ++j) acc[i][j] = f32x4{0.f, 0.f, 0.f, 0.f};

    const u16* Asrc = A + (m0 + srow) * (long)K + kbase + sg8;
    auto stageA = [&](int t, int slot) {
        char* dst = (char*)smA + slot * 32768 + wv * 1024;
        const u16* src = Asrc + t * 64;
        #pragma unroll
        for (int hj = 0; hj < 4; ++hj)
            glds16(src + (size_t)(hj * 64) * K, dst + hj * 8192);
    };
    auto stageB3 = [&](int t) {
        char* base = (char*)smB + (t & 1) * 24576;
        #pragma unroll
        for (int j = 0; j < 3; ++j) {
            long r = n0 + j * 64 + srow;
            if (r > blimit) r = blimit;
            glds16(B + (size_t)r * K + kbase + t * 64 + sg8,
                   base + (j * 64 + wv * 8) * 128);
        }
    };

    bf16x8 aq[4][2], s0[2][2], s1[2][2], s2[2][2];

    stageB3(0);
    stageA(0, 0);
    if (NT > 1) { stageA(1, 1); VMW(4); }
    else        { VMW(0); }
    BARB();
    READ_BQ(s2, bR, 0);
    READ_AQ(aR);

    int sA = 0;
    for (int t = 0; t < NT; ++t) {
        int sA1 = sA + 1; if (sA1 == 3) sA1 = 0;
        int sA2 = sA1 + 1; if (sA2 == 3) sA2 = 0;
        const char* bS  = bR + (t & 1) * 24576;
        const char* bS1 = bR + ((t + 1) & 1) * 24576;
        READ_BQ(s0, bS, 1);
        if (t + 1 < NT) stageB3(t + 1);
        if (t + 2 < NT) stageA(t + 2, sA2);
        MFMA_N(0, s2);
        SB0();
        READ_BQ(s1, bS, 2);
        MFMA_N(1, s0);
        SB0();
        MFMA_N(2, s1);
        if (t + 2 < NT)      VMW(4);
        else if (t + 1 < NT) VMW(0);
        BARB();
        if (t + 1 < NT) { READ_BQ(s2, bS1, 0); READ_AQ(aR + sA1 * 32768); }
        BARB();
        sA = sA1;
    }

    const int cr = (lane >> 4) * 4;
    const int cc = lane & 15;
    #pragma unroll
    for (int nf = 0; nf < 6; ++nf) {
        long col = n0 + wn2 * 96 + nf * 16 + cc;
        #pragma unroll
        for (int mi = 0; mi < 4; ++mi) {
            long row = m0 + wm2 * 64 + mi * 16 + cr;
            #pragma unroll
            for (int r2 = 0; r2 < 4; ++r2)
                C[(row + r2) * (long)N + col] = f2bf(acc[mi][nf][r2]);
        }
    }
}

// ------- R13 rope: K/V ONLY (Q-rope fused into attn) ---------------------------
// Reads only the 2KB K/V segment of each p1 row (was full 10.2KB) and drops the
// 16.8MB qrot write entirely: ~10us -> ~3us. K/V pre-rotated head-major as before.
__global__ __launch_bounds__(256) void rope_kernel(const u16* __restrict__ p1,
                                                   const float* __restrict__ b_qkv,
                                                   u16* __restrict__ kr,
                                                   u16* __restrict__ vr) {
    const int t = blockIdx.x;
    const int tid = threadIdx.x;
    __shared__ float cs[32], sn[32];
    if (tid < 32) {
        float fi = (float)tid;
        float freq   = exp2f(17.1946032f * (fi * (1.0f / 32.0f)));   // 150000^(i/32)
        float interp = 1.0f / (32.0f * freq);
        float extra  = 1.0f / freq;
        float ramp   = (fi - 8.0927802f) * (1.0f / (17.3980220f - 8.0927802f));
        float rc     = fminf(fmaxf(ramp, 0.0f), 1.0f);               // = 1 - mask
        float invf   = interp * rc + extra * (1.0f - rc);
        float ang    = (float)t * invf;
        cs[tid] = cosf(ang) * 1.3465736f;                            // * concentration
        sn[tid] = sinf(ang) * 1.3465736f;
    }
    __syncthreads();
    const u16* rowA = p1 + (long)t * QKVD;
    auto pair = [&](int col) -> float2 {
        float2 bb = *(const float2*)(b_qkv + col);
        u32 u = *(const u32*)(rowA + col);
        return make_float2(bflo(u) + bb.x, bfhi(u) + bb.y);
    };
    // K: 8 heads x 32 pairs == 256 threads; head-major layout [kv][t][64]
    {
        int kv = tid >> 5, i = tid & 31;
        float2 ab = pair(QD + kv * 64 + 2 * i);
        float o1 = ab.x * cs[i] - ab.y * sn[i];
        float o2 = ab.y * cs[i] + ab.x * sn[i];
        *(u32*)(kr + ((long)kv * TTOK + t) * HD + 2 * i) = (u32)f2bf(o1) | ((u32)f2bf(o2) << 16);
    }
    // V: 8 heads x 64 = 256 u32; head-major [kv][t][64]
    {
        int kv = tid >> 5, d2 = tid & 31;
        float2 ab = pair(QD + 512 + kv * 64 + 2 * d2);
        *(u32*)(vr + ((long)kv * TTOK + t) * HD + 2 * d2) = (u32)f2bf(ab.x) | ((u32)f2bf(ab.y) << 16);
    }
}

// -------- R13 attn: R9 structure + fused Q-bias+rope (reads p1 directly) -------
// Q rows t0..t0+15 x cols head*64 are a disjoint read-once partition of p1 with
// full cache-line use (128B/row/head) -- unlike R11's strided K/V reads, this
// fusion has no bad-locality failure mode. Per-block 16x32 cos/sin table (4KB
// LDS, one sincos/thread). Rounding points identical to split rope.
__global__ __launch_bounds__(512, 1) void attn_kernel(const u16* __restrict__ p1,
                                                      const float* __restrict__ b_qkv,
                                                      const u16* __restrict__ kr,
                                                      const u16* __restrict__ vr,
                                                      const float* __restrict__ sinks,
                                                      u16* __restrict__ o) {
    const int t0  = blockIdx.x * 16;
    const int h   = blockIdx.y;
    const int tid = threadIdx.x;
    const int lane = tid & 63, wv = tid >> 6;    // wv = q-head 0..7
    extern __shared__ __align__(16) u16 asmem[];
    u16* const ks = asmem;                        // [144][72]
    u16* const Vt = asmem + 10368;                // [64][168], cols 144..159 zero
    u16* const Pb = asmem + 21120;                // [8][16][168], cols 144..159 zero
    float* const csQ = (float*)(asmem + 42624);   // [16][32]
    float* const snQ = csQ + 512;                 // [16][32]
    const u16* kb = kr + (long)h * TTOK * HD;
    const u16* vb = vr + (long)h * TTOK * HD;

    // stage K rows (coalesced): 1152 uint4 over 512 threads
    #pragma unroll
    for (int i = 0; i < 3; ++i) {
        int idx = i * 512 + tid;
        if (idx < 144 * 8) {
            int rr = idx >> 3, c = idx & 7;
            int tk = t0 - 128 + rr;
            int tks = tk < 0 ? 0 : tk;
            *(uint4*)(ks + rr * 72 + c * 8) = *(const uint4*)(kb + (long)tks * HD + c * 8);
        }
    }
    // stage V transposed, pair-packed
    if (tid < 288) {
        const int kp = tid >> 2, c2 = tid & 3;
        const int k0 = kp * 2;
        int tk0 = t0 - 128 + k0;     tk0 = tk0 < 0 ? 0 : tk0;
        int tk1 = t0 - 128 + k0 + 1; tk1 = tk1 < 0 ? 0 : tk1;
        uint4 a0 = *(const uint4*)(vb + (long)tk0 * HD + c2 * 16);
        uint4 a1 = *(const uint4*)(vb + (long)tk0 * HD + c2 * 16 + 8);
        uint4 b0 = *(const uint4*)(vb + (long)tk1 * HD + c2 * 16);
        uint4 b1 = *(const uint4*)(vb + (long)tk1 * HD + c2 * 16 + 8);
        u32 wa[8] = {a0.x, a0.y, a0.z, a0.w, a1.x, a1.y, a1.z, a1.w};
        u32 wb[8] = {b0.x, b0.y, b0.z, b0.w, b1.x, b1.y, b1.z, b1.w};
        u16* vrow = Vt + c2 * 16 * 168 + k0;
        if (c2 & 2) {
            #pragma unroll
            for (int dd = 0; dd < 16; ++dd) {
                int d = (dd + 4) & 15;
                u32 oo = (d & 1) ? ((wa[d >> 1] >> 16) | (wb[d >> 1] & 0xffff0000u))
                                 : ((wa[d >> 1] & 0xffffu) | (wb[d >> 1] << 16));
                *(u32*)(vrow + d * 168) = oo;
            }
        } else {
            #pragma unroll
            for (int d = 0; d < 16; ++d) {
                u32 oo = (d & 1) ? ((wa[d >> 1] >> 16) | (wb[d >> 1] & 0xffff0000u))
                                 : ((wa[d >> 1] & 0xffffu) | (wb[d >> 1] << 16));
                *(u32*)(vrow + d * 168) = oo;
            }
        }
    }
    // Q-rope cos/sin table: rows t0..t0+15 (512 entries, one per thread)
    {
        int fi = tid & 31;
        float f = (float)fi;
        float freq   = exp2f(17.1946032f * (f * (1.0f / 32.0f)));
        float interp = 1.0f / (32.0f * freq);
        float extra  = 1.0f / freq;
        float ramp   = (f - 8.0927802f) * (1.0f / (17.3980220f - 8.0927802f));
        float rc     = fminf(fmaxf(ramp, 0.0f), 1.0f);
        float invf   = interp * rc + extra * (1.0f - rc);
        float ang    = (float)(t0 + (tid >> 5)) * invf;
        csQ[tid] = cosf(ang) * 1.3465736f;
        snQ[tid] = sinf(ang) * 1.3465736f;
    }
    if (tid < 128) {
        *(uint4*)(Vt + (tid >> 1) * 168 + 144 + (tid & 1) * 8) = uint4{0, 0, 0, 0};
    }
    if (lane < 32) {
        *(uint4*)(Pb + wv * 16 * 168 + (lane >> 1) * 168 + 144 + (lane & 1) * 8) = uint4{0, 0, 0, 0};
    }
    __syncthreads();

    const int head = h * QMULT + wv;
    const int fr = lane & 15, fk = (lane >> 4) * 8;
    const int cr = (lane >> 4) * 4;
    u16* const Pw = Pb + wv * 16 * 168;

    // Q: load from p1, add bias, rotate (all indices compile-time, rule #20)
    const u16* qrow = p1 + (long)(t0 + fr) * QKVD + head * HD;
    const float* bq = b_qkv + head * HD;
    const float* csQl = csQ + fr * 32;
    const float* snQl = snQ + fr * 32;
    u16 qtmp[16];
    #pragma unroll
    for (int half = 0; half < 2; ++half) {
        #pragma unroll
        for (int j = 0; j < 4; ++j) {
            const int base = half * 32 + fk;
            u32 w = *(const u32*)(qrow + base + 2 * j);
            float a0 = bflo(w) + bq[base + 2 * j];
            float a1 = bfhi(w) + bq[base + 2 * j + 1];
            float c = csQl[(base >> 1) + j], s = snQl[(base >> 1) + j];
            qtmp[half * 8 + 2 * j]     = f2bf(a0 * c - a1 * s);
            qtmp[half * 8 + 2 * j + 1] = f2bf(a1 * c + a0 * s);
        }
    }
    bf16x8 qf0 = *(const bf16x8*)&qtmp[0];
    bf16x8 qf1 = *(const bf16x8*)&qtmp[8];

    const int kmin = 128 - t0;
    float lsum[4] = {0.f, 0.f, 0.f, 0.f};

    for (int nt = 0; nt < 9; ++nt) {
        bf16x8 b0 = *(const bf16x8*)(ks + (nt * 16 + fr) * 72 + fk);
        bf16x8 b1 = *(const bf16x8*)(ks + (nt * 16 + fr) * 72 + 32 + fk);
        f32x4 s = f32x4{0.f, 0.f, 0.f, 0.f};
        s = __builtin_amdgcn_mfma_f32_16x16x32_bf16(qf0, b0, s, 0, 0, 0);
        s = __builtin_amdgcn_mfma_f32_16x16x32_bf16(qf1, b1, s, 0, 0, 0);
        const int kk = nt * 16 + fr;
        #pragma unroll
        for (int r = 0; r < 4; ++r) {
            int row = cr + r;
            bool valid = (kk >= row) && (kk <= row + 128) && (kk >= kmin);
            float p = valid ? __expf(s[r] * 0.125f) : 0.0f;
            lsum[r] += p;
            Pw[row * 168 + kk] = f2bf(p);
        }
    }

    f32x4 oacc[4];
    #pragma unroll
    for (int dt = 0; dt < 4; ++dt) oacc[dt] = f32x4{0.f, 0.f, 0.f, 0.f};
    #pragma unroll
    for (int k5 = 0; k5 < 5; ++k5) {
        const int k0 = k5 * 32;
        bf16x8 pa = *(const bf16x8*)(Pw + fr * 168 + k0 + fk);
        #pragma unroll
        for (int dt = 0; dt < 4; ++dt) {
            bf16x8 vf = *(const bf16x8*)(Vt + (dt * 16 + fr) * 168 + k0 + fk);
            oacc[dt] = __builtin_amdgcn_mfma_f32_16x16x32_bf16(pa, vf, oacc[dt], 0, 0, 0);
        }
    }

    #pragma unroll
    for (int r = 0; r < 4; ++r) {
        float v = lsum[r];
        v += __shfl_xor(v, 1);
        v += __shfl_xor(v, 2);
        v += __shfl_xor(v, 4);
        v += __shfl_xor(v, 8);
        lsum[r] = v;
    }
    const float sk = exp2f(sinks[head]);
    float inv[4];
    #pragma unroll
    for (int r = 0; r < 4; ++r) inv[r] = 1.0f / (lsum[r] + sk);

    #pragma unroll
    for (int dt = 0; dt < 4; ++dt) {
        #pragma unroll
        for (int r = 0; r < 4; ++r) {
            o[(long)(t0 + cr + r) * QD + head * HD + dt * 16 + fr] = f2bf(oacc[dt][r] * inv[r]);
        }
    }
}

// ---------------- reduce GEMM2 partials + bias + residual -> out ----------------
__global__ __launch_bounds__(256) void reduce2_kernel(const u16* __restrict__ p2a,
                                                      const u16* __restrict__ p2b,
                                                      const float* __restrict__ x,
                                                      const float* __restrict__ b_out,
                                                      float* __restrict__ out) {
    const int row = blockIdx.y;
    const int c4 = blockIdx.x * 256 + threadIdx.x;   // float4 index within row
    if (c4 >= 720) return;
    const int col = c4 * 4;
    ushort4 ua = *(const ushort4*)(p2a + (long)row * NPAD + col);
    ushort4 ub = *(const ushort4*)(p2b + (long)row * NPAD + col);
    float4 xv = *(const float4*)(x + (long)row * HIDDEN + col);
    float4 bv = *(const float4*)(b_out + col);
    float4 o;
    o.x = xv.x + bv.x + __uint_as_float((u32)ua.x << 16) + __uint_as_float((u32)ub.x << 16);
    o.y = xv.y + bv.y + __uint_as_float((u32)ua.y << 16) + __uint_as_float((u32)ub.y << 16);
    o.z = xv.z + bv.z + __uint_as_float((u32)ua.z << 16) + __uint_as_float((u32)ub.z << 16);
    o.w = xv.w + bv.w + __uint_as_float((u32)ua.w << 16) + __uint_as_float((u32)ub.w << 16);
    *(float4*)(out + (long)row * HIDDEN + col) = o;
}

// ---------------- launcher ----------------
extern "C" void kernel_launch(void* const* d_in, const int* in_sizes, int n_in,
                              void* d_out, int out_size, void* d_ws, size_t ws_size,
                              hipStream_t stream) {
    const float* x      = (const float*)d_in[0];
    const float* nscale = (const float*)d_in[1];
    const float* w_qkv  = (const float*)d_in[2];
    const float* b_qkv  = (const float*)d_in[3];
    const float* sinks  = (const float*)d_in[4];
    const float* w_out  = (const float*)d_in[5];
    const float* b_out  = (const float*)d_in[6];
    float* out = (float*)d_out;

    static int smem_set = 0;
    if (!smem_set) {
        hipFuncSetAttribute((const void*)gemm_bt_8ph,
                            hipFuncAttributeMaxDynamicSharedMemorySize, 163840);
        hipFuncSetAttribute((const void*)gemm_bt_3q,
                            hipFuncAttributeMaxDynamicSharedMemorySize, 147456);
        hipFuncSetAttribute((const void*)attn_kernel,
                            hipFuncAttributeMaxDynamicSharedMemorySize, 89344);
        smem_set = 1;
    }

    char* ws = (char*)d_ws;
    size_t off = 0;
    auto alloc = [&](size_t bytes) { void* p = ws + off; off += (bytes + 255) & ~(size_t)255; return p; };
    const size_t p1_bytes  = (size_t)TTOK * QKVD * 2;          // 21.0 MB (GEMM1 out)
    const size_t p2_bytes  = (size_t)2 * TTOK * NPAD * 2;      // 25.2 MB (GEMM2 partials)
    u16* wqkv_bf = (u16*)alloc((size_t)QKVD * HIDDEN * 2);     // 29.5 MB
    u16* wout_bf = (u16*)alloc((size_t)NPAD * QD * 2);         // 25.2 MB
    u16* h       = (u16*)alloc((size_t)TTOK * HIDDEN * 2);     // 11.8 MB
    u16* p1      = (u16*)alloc(p1_bytes > p2_bytes ? p1_bytes : p2_bytes);
    // aliases (dead-after analysis):
    u16* attn = wqkv_bf;                       // wqkv_bf dead after gemm1 (16.8 MB)
    u16* krot = wqkv_bf + (size_t)TTOK * QD;   // wqkv tail: +2.1 MB
    u16* vrot = krot + (size_t)NKV * TTOK * HD;// +2.1 MB (total 21.0 <= 29.5 OK)
    u16* p2   = p1;                            // p1 dead after attn (GEMM2 writes after)

    prep_kernel<<<PREP_QKV_BLOCKS + PREP_RMS_BLOCKS, 256, 0, stream>>>(
        w_qkv, wqkv_bf, x, nscale, h);
    // GEMM1: full-K, 160 gemm blocks + 96 working filler blocks (z=1; rest exit)
    gemm_bt_8ph<<<dim3(QKVD / 256, TTOK / 256, 2), 512, 163840, stream>>>(
        h, wqkv_bf, p1, QKVD, HIDDEN, HIDDEN, QKVD - 1, QKVD, 1, 96, w_out, wout_bf);
    // rope: K/V only (Q fused into attn)
    rope_kernel<<<TTOK, 256, 0, stream>>>(p1, b_qkv, krot, vrot);
    // attn: merged-z + fused Q-rope, 128x8 = 1024 blocks x 512 thr, 87 KB LDS
    attn_kernel<<<dim3(TTOK / 16, NKV), 512, 89344, stream>>>(
        p1, b_qkv, krot, vrot, sinks, attn);
    // GEMM2: 256x192 tiles, split-K z=2 -> 16x8x2 = 256 blocks (full fill)
    gemm_bt_3q<<<dim3(NPAD / 192, TTOK / 256, 2), 512, 147456, stream>>>(
        attn, wout_bf, p2, NPAD, QD, QD / 2, NPAD - 1);
    reduce2_kernel<<<dim3(3, TTOK), 256, 0, stream>>>(
        p2, p2 + (size_t)TTOK * NPAD, x, b_out, out);
}